// Round 15
// baseline (58.751 us; speedup 1.0000x reference)
//
#include <hip/hip_runtime.h>
#include <hip/hip_bf16.h>

// ---------------------------------------------------------------------------
// R15: occupancy fix via REGISTER DIET (R14 evidence: latency-bound at
// 2 waves/SIMD, grid=1 block/CU; ~1550cy stall per ~200cy-compute tile).
//   - j=32 per block -> grid 512 -> 2 blocks/CU = 4 waves/SIMD (2x overlap)
//   - regs: B 16 + acc 32(AGPR) + 2 sets x 16 + misc ~= 100 <= lb(512,4) cap
//     of 128 (R13 spilled because it needed ~150 under a 64 cap)
//   - merged pvF pairs (cb0||cb1),(cb2||cb3): 4x16B loads/tile (was 6)
// Math (validated R8-R14): gap_att[c]=sum_j W[j,c]/Z[j], W=sum_i p_ij v[i,c],
// Z=sum_i p_ij, p=exp2(e2), v=pr+pd; fragment-order global layouts.
// ---------------------------------------------------------------------------

typedef __bf16 bf16;
typedef __bf16 bf16x4 __attribute__((ext_vector_type(4)));
typedef __bf16 bf16x8 __attribute__((ext_vector_type(8)));
typedef float  f32x4  __attribute__((ext_vector_type(4)));
typedef float  float4v __attribute__((ext_vector_type(4)));
typedef short  s4     __attribute__((ext_vector_type(4)));

#define MFMA_BF16(a, b, c) __builtin_amdgcn_mfma_f32_16x16x32_bf16((a), (b), (c), 0, 0, 0)

#if defined(__has_builtin)
# if __has_builtin(__builtin_amdgcn_mfma_f32_16x16x16bf16_1k)
#  define MFMA16_BUILTIN(a, b, c) __builtin_amdgcn_mfma_f32_16x16x16bf16_1k((a), (b), (c), 0, 0, 0)
# elif __has_builtin(__builtin_amdgcn_mfma_f32_16x16x16_bf16)
#  define MFMA16_BUILTIN(a, b, c) __builtin_amdgcn_mfma_f32_16x16x16_bf16((a), (b), (c), 0, 0, 0)
# endif
#endif

__device__ __forceinline__ f32x4 MFMA16(s4 a, s4 b, f32x4 c) {
#ifdef MFMA16_BUILTIN
    return MFMA16_BUILTIN(a, b, c);
#else
    asm("v_mfma_f32_16x16x16_bf16 %0, %1, %2, %0" : "+v"(c) : "v"(a), "v"(b));
    return c;
#endif
}

#if defined(__has_builtin)
# if __has_builtin(__builtin_amdgcn_exp2f)
#  define EXP2(x) __builtin_amdgcn_exp2f(x)
# else
#  define EXP2(x) exp2f(x)
# endif
#else
# define EXP2(x) exp2f(x)
#endif

#define K_E 0.18033688f      // 0.125 * log2(e)

__device__ __forceinline__ int swz128(int row, int colByte) {
    return row * 128 + (colByte ^ ((row & 7) << 4));
}
__device__ __forceinline__ int swz512(int row, int colByte) {
    return row * 512 + (colByte ^ ((row & 15) << 4));
}
__device__ __forceinline__ bf16x4 lo8(bf16x8 x) {
    bf16x4 r; r[0] = x[0]; r[1] = x[1]; r[2] = x[2]; r[3] = x[3]; return r;
}
__device__ __forceinline__ bf16x4 hi8(bf16x8 x) {
    bf16x4 r; r[0] = x[4]; r[1] = x[5]; r[2] = x[6]; r[3] = x[7]; return r;
}

// LDS union offsets for K_A
#define OW_W   0
#define OW_WR  32768
#define OW_WD  40960
#define OT_C   0
#define OT_R   16384
#define OT_D   20480
#define O_S1   49152
#define O_B1   49408
#define O_RED  49664
#define SMEMA  51712

// ---------------------------------------------------------------------------
// K_A: self-staged weights -> conv+BN+ReLU -> proj -> fragment-order stores.
// prF/pdF: f(i,c) = (i>>4)*1024 + (c>>3)*128 + (i&15)*8 + (c&7)
// pvF:     g(c,i) = (i>>4)*1024 + (c>>5)*512 + (((i>>2)&3)*16 + (c&15))*8
//                   + ((c>>4)&1)*4 + (i&3)     [paired cb frags per 16B lane]
// ---------------------------------------------------------------------------
__global__ __launch_bounds__(512, 2) void k_front(
    const float* __restrict__ rgb, const float* __restrict__ dep,
    const float* __restrict__ conv_w,
    const float* __restrict__ bn1_g, const float* __restrict__ bn1_b,
    const float* __restrict__ bn1_m, const float* __restrict__ bn1_v,
    const float* __restrict__ rgb_w, const float* __restrict__ dep_w,
    bf16* __restrict__ prF, bf16* __restrict__ pdF, bf16* __restrict__ pvF,
    float* __restrict__ rgbdPart, int* __restrict__ counter)
{
    const int bid = blockIdx.x;
    const int xcd = bid & 7;
    const int b    = xcd >> 1;
    const int tile = ((bid >> 3) << 1) | (xcd & 1);
    const int p0   = tile * 32;
    const int tid = threadIdx.x;
    const int w   = tid >> 6;
    const int lane = tid & 63;
    const int l15 = lane & 15;
    const int lg  = lane >> 4;
    const int ot4 = w & 3;
    const int ot  = ot4 * 16;
    const int ph  = w >> 2;

    if (bid == 0 && tid == 0) *counter = 0;

    __shared__ __align__(16) unsigned char smem[SMEMA];
    float* s1 = (float*)(smem + O_S1);
    float* b1 = (float*)(smem + O_B1);
    float* red = (float*)(smem + O_RED);

    // ---- phase W: stage all weights coalesced -> swizzled LDS bf16 ----
    {
        unsigned char* ldsW  = smem + OW_W;
        unsigned char* ldsWR = smem + OW_WR;
        unsigned char* ldsWD = smem + OW_WD;
        #pragma unroll
        for (int q = 0; q < 8; ++q) {
            const int idx = (q * 512 + tid) * 4;
            float4v v = *(const float4v*)(conv_w + idx);
            const int o = idx >> 8, c = idx & 255;
            bf16x4 h;
            #pragma unroll
            for (int j = 0; j < 4; ++j) h[j] = (bf16)v[j];
            *(bf16x4*)(ldsW + swz512(o, c * 2)) = h;
        }
        #pragma unroll
        for (int q = 0; q < 2; ++q) {
            const int idx = (q * 512 + tid) * 4;
            const int o = idx >> 6, c = idx & 63;
            float4v v = *(const float4v*)(rgb_w + idx);
            bf16x4 h;
            #pragma unroll
            for (int j = 0; j < 4; ++j) h[j] = (bf16)v[j];
            *(bf16x4*)(ldsWR + swz128(o, c * 2)) = h;
            v = *(const float4v*)(dep_w + idx);
            #pragma unroll
            for (int j = 0; j < 4; ++j) h[j] = (bf16)v[j];
            *(bf16x4*)(ldsWD + swz128(o, c * 2)) = h;
        }
        if (tid < 64) {
            float sc = bn1_g[tid] * rsqrtf(bn1_v[tid] + 1e-5f);
            s1[tid] = sc;
            b1[tid] = bn1_b[tid] - bn1_m[tid] * sc;
        }
    }
    __syncthreads();

    // ---- fragments -> registers ----
    bf16x8 aW[8], aR[2], aD[2];
    {
        const unsigned char* ldsW  = smem + OW_W;
        const unsigned char* ldsWR = smem + OW_WR;
        const unsigned char* ldsWD = smem + OW_WD;
        const int row = ot + l15;
        #pragma unroll
        for (int kk = 0; kk < 8; ++kk)
            aW[kk] = *(const bf16x8*)(ldsW + swz512(row, (kk * 32 + lg * 8) * 2));
        #pragma unroll
        for (int kk = 0; kk < 2; ++kk) {
            aR[kk] = *(const bf16x8*)(ldsWR + swz128(row, (kk * 32 + lg * 8) * 2));
            aD[kk] = *(const bf16x8*)(ldsWD + swz128(row, (kk * 32 + lg * 8) * 2));
        }
    }
    __syncthreads();

    // ---- phase T: stage dep/rgb tiles coalesced ----
    unsigned char* ldsC = smem + OT_C;
    unsigned char* ldsR = smem + OT_R;
    unsigned char* ldsD = smem + OT_D;
    const float* depb = dep + (size_t)b * 256 * 4096;
    const float* rgbb = rgb + (size_t)b * 64 * 4096;
    {
        const int c0 = tid >> 3, seg = tid & 7;
        #pragma unroll
        for (int r = 0; r < 4; ++r) {
            const int c = r * 64 + c0;
            float4v v = *(const float4v*)(depb + (size_t)c * 4096 + p0 + seg * 4);
            #pragma unroll
            for (int k = 0; k < 4; ++k)
                *(bf16*)(ldsC + swz512(seg * 4 + k, c * 2)) = (bf16)v[k];
        }
        float4v v = *(const float4v*)(rgbb + (size_t)c0 * 4096 + p0 + seg * 4);
        #pragma unroll
        for (int k = 0; k < 4; ++k)
            *(bf16*)(ldsR + swz128(seg * 4 + k, c0 * 2)) = (bf16)v[k];
    }
    __syncthreads();

    // ---- conv MFMA K=256 ----
    const int prow = ph * 16 + l15;
    f32x4 acc = {0.f, 0.f, 0.f, 0.f};
    #pragma unroll
    for (int kk = 0; kk < 8; ++kk) {
        bf16x8 bF = *(const bf16x8*)(ldsC + swz512(prow, (kk * 32 + lg * 8) * 2));
        acc = MFMA_BF16(aW[kk], bF, acc);
    }
    {
        const int o0 = ot + lg * 4;
        bf16x4 v4;
        #pragma unroll
        for (int r = 0; r < 4; ++r) {
            float x = acc[r] * s1[o0 + r] + b1[o0 + r];
            v4[r] = (bf16)(x > 0.f ? x : 0.f);
        }
        *(bf16x4*)(ldsD + swz128(prow, o0 * 2)) = v4;
    }
    __syncthreads();

    // ---- proj GEMMs (K=64) + fragment-order stores ----
    f32x4 accR = {0.f, 0.f, 0.f, 0.f}, accD = {0.f, 0.f, 0.f, 0.f};
    #pragma unroll
    for (int kk = 0; kk < 2; ++kk) {
        const int cb = (kk * 32 + lg * 8) * 2;
        bf16x8 bR = *(const bf16x8*)(ldsR + swz128(prow, cb));
        bf16x8 bD = *(const bf16x8*)(ldsD + swz128(prow, cb));
        accR = MFMA_BF16(aR[kk], bR, accR);
        accD = MFMA_BF16(aD[kk], bD, accD);
    }
    {
        const int o0 = ot + lg * 4;
        const size_t itile = (size_t)tile * 2 + ph;
        const size_t fbase = (size_t)b * 262144 + itile * 1024;
        const size_t prOff = fbase + (size_t)(o0 >> 3) * 128 + l15 * 8 + (o0 & 7);
        bf16x4 vR, vD;
        #pragma unroll
        for (int r = 0; r < 4; ++r) {
            vR[r] = (bf16)(accR[r] * K_E);
            vD[r] = (bf16)accD[r];
        }
        *(bf16x4*)(prF + prOff) = vR;
        *(bf16x4*)(pdF + prOff) = vD;
        // pvF paired layout (see header); i_local = l15
        const size_t pvBase = fbase + (ot4 >> 1) * 512 + (l15 >> 2) * 128
                            + lg * 32 + (ot4 & 1) * 4 + (l15 & 3);
        #pragma unroll
        for (int r = 0; r < 4; ++r)
            pvF[pvBase + r * 8] = (bf16)(accR[r] + accD[r]);
    }

    // ---- rgbd per-tile sums ----
    {
        const int c = tid & 63, g8 = tid >> 6;
        float sum = 0.f;
        #pragma unroll
        for (int q = 0; q < 4; ++q) {
            const int pp = g8 * 4 + q;
            sum += (float)*(const bf16*)(ldsR + swz128(pp, c * 2))
                 + (float)*(const bf16*)(ldsD + swz128(pp, c * 2));
        }
        red[g8 * 64 + c] = sum;
    }
    __syncthreads();
    if (tid < 64) {
        float s = 0.f;
        #pragma unroll
        for (int g = 0; g < 8; ++g) s += red[g * 64 + tid];
        rgbdPart[((size_t)b * 128 + tile) * 64 + tid] = s;
    }
}

// ---------------------------------------------------------------------------
// K_B: single-pass column stats, j=32/block (register diet), depth-2 named
// prefetch, 4 x 16B loads/tile. 512 blocks (4b x 128 j-chunks) x 512 thr,
// lb(512,4) = 128-reg cap (usage ~100). Last-block-done MLP gate.
// ---------------------------------------------------------------------------
#define LOADSET(A0, A1, V01, V23, q)                                          \
    {                                                                         \
        const bf16* pA_ = prb + (size_t)((q) * 8 + ih) * 1024;                \
        const bf16* pV_ = pvb + (size_t)((q) * 8 + ih) * 1024;                \
        A0  = *(const bf16x8*)(pA_ + lane * 8);                               \
        A1  = *(const bf16x8*)(pA_ + 512 + lane * 8);                         \
        V01 = *(const bf16x8*)(pV_ + lane * 8);                               \
        V23 = *(const bf16x8*)(pV_ + 512 + lane * 8);                         \
    }

#define COMPUTESET(A0, A1, V01, V23)                                          \
    {                                                                         \
        const s4 v0_ = __builtin_bit_cast(s4, lo8(V01));                      \
        const s4 v1_ = __builtin_bit_cast(s4, hi8(V01));                      \
        const s4 v2_ = __builtin_bit_cast(s4, lo8(V23));                      \
        const s4 v3_ = __builtin_bit_cast(s4, hi8(V23));                      \
        _Pragma("unroll")                                                     \
        for (int jt = 0; jt < 2; ++jt) {                                      \
            f32x4 e = {0.f, 0.f, 0.f, 0.f};                                   \
            e = MFMA_BF16(A0, B0[jt], e);                                     \
            e = MFMA_BF16(A1, B1[jt], e);                                     \
            bf16x4 ph_;                                                       \
            _Pragma("unroll")                                                 \
            for (int r = 0; r < 4; ++r) {                                     \
                float pf_ = EXP2(e[r]);                                       \
                z[jt] += pf_;                                                 \
                ph_[r] = (bf16)pf_;                                           \
            }                                                                 \
            const s4 pB_ = __builtin_bit_cast(s4, ph_);                       \
            acc[jt][0] = MFMA16(v0_, pB_, acc[jt][0]);                        \
            acc[jt][1] = MFMA16(v1_, pB_, acc[jt][1]);                        \
            acc[jt][2] = MFMA16(v2_, pB_, acc[jt][2]);                        \
            acc[jt][3] = MFMA16(v3_, pB_, acc[jt][3]);                        \
        }                                                                     \
    }

__global__ __launch_bounds__(512, 4) void k_col(
    const bf16* __restrict__ prF, const bf16* __restrict__ pdF,
    const bf16* __restrict__ pvF,
    float* __restrict__ gapPart, const float* __restrict__ rgbdPart,
    int* __restrict__ counter,
    const float* __restrict__ mlp1_w,
    const float* __restrict__ bn2_g, const float* __restrict__ bn2_b,
    const float* __restrict__ bn2_m, const float* __restrict__ bn2_v,
    const float* __restrict__ mlp2_w,
    const float* __restrict__ bn3_g, const float* __restrict__ bn3_b,
    const float* __restrict__ bn3_m, const float* __restrict__ bn3_v,
    float* __restrict__ out)
{
    const int bid = blockIdx.x;
    const int xcd = bid & 7, b = xcd >> 1;
    const int jc = ((bid >> 3) << 1) | (xcd & 1);     // 0..127 (32 j each)
    const int tid = threadIdx.x;
    const int ih = tid >> 6, lane = tid & 63;
    const int l15 = lane & 15, lg = lane >> 4;

    __shared__ float zred[8][32];
    __shared__ float zfull[32];
    __shared__ float gred[8][64];
    __shared__ float gv4[4][64];
    __shared__ float h4[4][24];
    __shared__ int winflag;
    if (tid == 0) winflag = 0;

    const bf16* prb = prF + (size_t)b * 262144;
    const bf16* pdb = pdF + (size_t)b * 262144;
    const bf16* pvb = pvF + (size_t)b * 262144;

    // resident b-frags for 2 j-subtiles
    bf16x8 B0[2], B1[2];
    #pragma unroll
    for (int jt = 0; jt < 2; ++jt) {
        const bf16* q = pdb + (size_t)(jc * 2 + jt) * 1024 + lane * 8;
        B0[jt] = *(const bf16x8*)q;
        B1[jt] = *(const bf16x8*)(q + 512);
    }

    f32x4 acc[2][4];
    #pragma unroll
    for (int jt = 0; jt < 2; ++jt)
        #pragma unroll
        for (int cb = 0; cb < 4; ++cb)
            acc[jt][cb] = (f32x4){0.f, 0.f, 0.f, 0.f};
    float z[2] = {0.f, 0.f};

    // depth-2 prefetch, named sets
    bf16x8 a0A, a1A, v01A, v23A, a0B, a1B, v01B, v23B;
    LOADSET(a0A, a1A, v01A, v23A, 0);
    LOADSET(a0B, a1B, v01B, v23B, 1);

    for (int t = 0; t < 32; t += 2) {
        COMPUTESET(a0A, a1A, v01A, v23A);
        if (t + 2 < 32) LOADSET(a0A, a1A, v01A, v23A, t + 2);
        COMPUTESET(a0B, a1B, v01B, v23B);
        if (t + 3 < 32) LOADSET(a0B, a1B, v01B, v23B, t + 3);
    }

    // ---- Z reduce (32 j) ----
    #pragma unroll
    for (int jt = 0; jt < 2; ++jt) {
        float zv = z[jt];
        zv += __shfl_xor(zv, 16);
        zv += __shfl_xor(zv, 32);
        if (lane < 16) zred[ih][jt * 16 + lane] = zv;
    }
    __syncthreads();
    if (tid < 32) {
        float s = 0.f;
        #pragma unroll
        for (int k = 0; k < 8; ++k) s += zred[k][tid];
        zfull[tid] = s;
    }
    __syncthreads();

    // ---- g[c] = sum_jt sum_l15 acc*zinv ----
    float zinv[2];
    #pragma unroll
    for (int jt = 0; jt < 2; ++jt) {
        const float zj = zfull[jt * 16 + l15];
        float zi = __builtin_amdgcn_rcpf(zj);
        zinv[jt] = zi * (2.0f - zj * zi);
    }
    #pragma unroll
    for (int cb = 0; cb < 4; ++cb) {
        #pragma unroll
        for (int r = 0; r < 4; ++r) {
            float v = acc[0][cb][r] * zinv[0] + acc[1][cb][r] * zinv[1];
            v += __shfl_xor(v, 1);
            v += __shfl_xor(v, 2);
            v += __shfl_xor(v, 4);
            v += __shfl_xor(v, 8);
            if (l15 == 0) gred[ih][cb * 16 + lg * 4 + r] = v;
        }
    }
    __syncthreads();
    if (tid < 64) {
        float s = 0.f;
        #pragma unroll
        for (int k = 0; k < 8; ++k) s += gred[k][tid];
        gapPart[((size_t)b * 128 + jc) * 64 + tid] = s;
        __threadfence();
        int old = atomicAdd(counter, 1);
        if (old == 512 * 64 - 1) winflag = 1;
    }
    __syncthreads();

    // ================= last block: MLP gate ==================
    if (winflag) {
        __threadfence();
        const int wb = ih >> 1, half = ih & 1;
        float acc2 = 0.f;
        const float* gp = gapPart + ((size_t)wb * 128 + half * 64) * 64 + lane;
        #pragma unroll 4
        for (int r = 0; r < 64; ++r) acc2 += gp[r * 64];
        const float* rp = rgbdPart + ((size_t)wb * 128 + half * 64) * 64 + lane;
        #pragma unroll 4
        for (int r = 0; r < 64; ++r) acc2 += rp[r * 64];
        gred[ih][lane] = acc2;
        __syncthreads();
        if (tid < 256) {
            const int b4 = tid >> 6, c = tid & 63;
            gv4[b4][c] = (gred[2 * b4][c] + gred[2 * b4 + 1][c]) * (1.f / 4096.f);
        }
        __syncthreads();
        if (tid < 96) {
            const int b4 = tid / 24, o = tid % 24;
            float a = 0.f;
            #pragma unroll
            for (int cc = 0; cc < 64; ++cc) a += mlp1_w[o * 64 + cc] * gv4[b4][cc];
            float sc = bn2_g[o] * rsqrtf(bn2_v[o] + 1e-5f);
            a = a * sc + bn2_b[o] - bn2_m[o] * sc;
            h4[b4][o] = a > 0.f ? a : 0.f;
        }
        __syncthreads();
        if (tid < 256) {
            const int b4 = tid >> 6, c = tid & 63;
            float u = 0.f;
            #pragma unroll
            for (int o = 0; o < 24; ++o) u += mlp2_w[c * 24 + o] * h4[b4][o];
            float sc = bn3_g[c] * rsqrtf(bn3_v[c] + 1e-5f);
            u = u * sc + bn3_b[c] - bn3_m[c] * sc;
            out[b4 * 64 + c] = 1.f / (1.f + __expf(-u));
        }
    }
}

// ---------------------------------------------------------------------------
extern "C" void kernel_launch(void* const* d_in, const int* in_sizes, int n_in,
                              void* d_out, int out_size, void* d_ws, size_t ws_size,
                              hipStream_t stream)
{
    const float* rgb    = (const float*)d_in[0];
    const float* dep    = (const float*)d_in[1];
    const float* conv_w = (const float*)d_in[2];
    const float* bn1_g  = (const float*)d_in[3];
    const float* bn1_b  = (const float*)d_in[4];
    const float* bn1_m  = (const float*)d_in[5];
    const float* bn1_v  = (const float*)d_in[6];
    const float* rgb_w  = (const float*)d_in[7];
    const float* dep_w  = (const float*)d_in[8];
    const float* mlp1_w = (const float*)d_in[9];
    const float* bn2_g  = (const float*)d_in[10];
    const float* bn2_b  = (const float*)d_in[11];
    const float* bn2_m  = (const float*)d_in[12];
    const float* bn2_v  = (const float*)d_in[13];
    const float* mlp2_w = (const float*)d_in[14];
    const float* bn3_g  = (const float*)d_in[15];
    const float* bn3_b  = (const float*)d_in[16];
    const float* bn3_m  = (const float*)d_in[17];
    const float* bn3_v  = (const float*)d_in[18];

    char* ws = (char*)d_ws;
    bf16*  prF      = (bf16*)(ws);                                  // 2 MB
    bf16*  pdF      = (bf16*)(ws + (2u << 20));                     // 2 MB
    bf16*  pvF      = (bf16*)(ws + (4u << 20));                     // 2 MB
    float* rgbdPart = (float*)(ws + (6u << 20));                    // 128 KB
    float* gapPart  = (float*)(ws + (6u << 20) + (128u << 10));     // 128 KB
    int*   counter  = (int*)  (ws + (6u << 20) + (256u << 10));     // 4 B

    k_front<<<512, 512, 0, stream>>>(rgb, dep, conv_w,
                                     bn1_g, bn1_b, bn1_m, bn1_v,
                                     rgb_w, dep_w,
                                     prF, pdF, pvF, rgbdPart, counter);
    k_col<<<512, 512, 0, stream>>>(prF, pdF, pvF, gapPart, rgbdPart, counter,
                                   mlp1_w, bn2_g, bn2_b, bn2_m, bn2_v,
                                   mlp2_w, bn3_g, bn3_b, bn3_m, bn3_v,
                                   (float*)d_out);
}

// Round 16
// 53.021 us; speedup vs baseline: 1.1081x; 1.1081x over previous
//
#include <hip/hip_runtime.h>
#include <hip/hip_bf16.h>

// ---------------------------------------------------------------------------
// R16: k_col with ASYNC global_load_lds staging (deep in-flight pipeline).
// R12/R14/R15 evidence: register-prefetch streaming delivers BW proportional
// to resident waves (5.8->10.1 TB/s for 2x waves) => concurrency-limited, far
// under the ~56 B/cy/CU L2 ceiling. Fix: fire-and-forget DMA (global_load_lds
// width 16) with counted vmcnt — in-flight bytes without VGPR cost (m97 lever).
//   - grid 256 (j=64/block, jt=4; minimal 256MB traffic), 512 thr, no barriers:
//     each wave stages & consumes its own 4KB/super-tile slice (dbuf 8KB/wave).
//   - s_waitcnt vmcnt(4) steady-state (never 0 mid-loop); lgkmcnt(0) before
//     slot overwrite; asm memory clobbers pin ordering.
// Math (validated R8-R15): gap_att[c]=sum_j W[j,c]/Z[j], W=sum_i p_ij v[i,c],
// Z=sum_i p_ij, p=exp2(e2), v=pr+pd; fragment-order layouts; paired pvF.
// K_A (k_front) unchanged from R15.
// ---------------------------------------------------------------------------

typedef __bf16 bf16;
typedef __bf16 bf16x4 __attribute__((ext_vector_type(4)));
typedef __bf16 bf16x8 __attribute__((ext_vector_type(8)));
typedef float  f32x4  __attribute__((ext_vector_type(4)));
typedef float  float4v __attribute__((ext_vector_type(4)));
typedef short  s4     __attribute__((ext_vector_type(4)));

#define MFMA_BF16(a, b, c) __builtin_amdgcn_mfma_f32_16x16x32_bf16((a), (b), (c), 0, 0, 0)

#if defined(__has_builtin)
# if __has_builtin(__builtin_amdgcn_mfma_f32_16x16x16bf16_1k)
#  define MFMA16_BUILTIN(a, b, c) __builtin_amdgcn_mfma_f32_16x16x16bf16_1k((a), (b), (c), 0, 0, 0)
# elif __has_builtin(__builtin_amdgcn_mfma_f32_16x16x16_bf16)
#  define MFMA16_BUILTIN(a, b, c) __builtin_amdgcn_mfma_f32_16x16x16_bf16((a), (b), (c), 0, 0, 0)
# endif
#endif

__device__ __forceinline__ f32x4 MFMA16(s4 a, s4 b, f32x4 c) {
#ifdef MFMA16_BUILTIN
    return MFMA16_BUILTIN(a, b, c);
#else
    asm("v_mfma_f32_16x16x16_bf16 %0, %1, %2, %0" : "+v"(c) : "v"(a), "v"(b));
    return c;
#endif
}

#if defined(__has_builtin)
# if __has_builtin(__builtin_amdgcn_exp2f)
#  define EXP2(x) __builtin_amdgcn_exp2f(x)
# else
#  define EXP2(x) exp2f(x)
# endif
#else
# define EXP2(x) exp2f(x)
#endif

#define K_E 0.18033688f      // 0.125 * log2(e)

__device__ __forceinline__ int swz128(int row, int colByte) {
    return row * 128 + (colByte ^ ((row & 7) << 4));
}
__device__ __forceinline__ int swz512(int row, int colByte) {
    return row * 512 + (colByte ^ ((row & 15) << 4));
}
__device__ __forceinline__ bf16x4 lo8(bf16x8 x) {
    bf16x4 r; r[0] = x[0]; r[1] = x[1]; r[2] = x[2]; r[3] = x[3]; return r;
}
__device__ __forceinline__ bf16x4 hi8(bf16x8 x) {
    bf16x4 r; r[0] = x[4]; r[1] = x[5]; r[2] = x[6]; r[3] = x[7]; return r;
}

__device__ __forceinline__ void gload_lds16(const void* g, void* l) {
    __builtin_amdgcn_global_load_lds(
        (const __attribute__((address_space(1))) void*)g,
        (__attribute__((address_space(3))) void*)l, 16, 0, 0);
}

// LDS union offsets for K_A
#define OW_W   0
#define OW_WR  32768
#define OW_WD  40960
#define OT_C   0
#define OT_R   16384
#define OT_D   20480
#define O_S1   49152
#define O_B1   49408
#define O_RED  49664
#define SMEMA  51712

// ---------------------------------------------------------------------------
// K_A: self-staged weights -> conv+BN+ReLU -> proj -> fragment-order stores.
// prF/pdF: f(i,c) = (i>>4)*1024 + (c>>3)*128 + (i&15)*8 + (c&7)
// pvF paired: g(c,i) = (i>>4)*1024 + (c>>5)*512 + (((i>>2)&3)*16+(c&15))*8
//             + ((c>>4)&1)*4 + (i&3)
// ---------------------------------------------------------------------------
__global__ __launch_bounds__(512, 2) void k_front(
    const float* __restrict__ rgb, const float* __restrict__ dep,
    const float* __restrict__ conv_w,
    const float* __restrict__ bn1_g, const float* __restrict__ bn1_b,
    const float* __restrict__ bn1_m, const float* __restrict__ bn1_v,
    const float* __restrict__ rgb_w, const float* __restrict__ dep_w,
    bf16* __restrict__ prF, bf16* __restrict__ pdF, bf16* __restrict__ pvF,
    float* __restrict__ rgbdPart, int* __restrict__ counter)
{
    const int bid = blockIdx.x;
    const int xcd = bid & 7;
    const int b    = xcd >> 1;
    const int tile = ((bid >> 3) << 1) | (xcd & 1);
    const int p0   = tile * 32;
    const int tid = threadIdx.x;
    const int w   = tid >> 6;
    const int lane = tid & 63;
    const int l15 = lane & 15;
    const int lg  = lane >> 4;
    const int ot4 = w & 3;
    const int ot  = ot4 * 16;
    const int ph  = w >> 2;

    if (bid == 0 && tid == 0) *counter = 0;

    __shared__ __align__(16) unsigned char smem[SMEMA];
    float* s1 = (float*)(smem + O_S1);
    float* b1 = (float*)(smem + O_B1);
    float* red = (float*)(smem + O_RED);

    // ---- phase W: stage all weights coalesced -> swizzled LDS bf16 ----
    {
        unsigned char* ldsW  = smem + OW_W;
        unsigned char* ldsWR = smem + OW_WR;
        unsigned char* ldsWD = smem + OW_WD;
        #pragma unroll
        for (int q = 0; q < 8; ++q) {
            const int idx = (q * 512 + tid) * 4;
            float4v v = *(const float4v*)(conv_w + idx);
            const int o = idx >> 8, c = idx & 255;
            bf16x4 h;
            #pragma unroll
            for (int j = 0; j < 4; ++j) h[j] = (bf16)v[j];
            *(bf16x4*)(ldsW + swz512(o, c * 2)) = h;
        }
        #pragma unroll
        for (int q = 0; q < 2; ++q) {
            const int idx = (q * 512 + tid) * 4;
            const int o = idx >> 6, c = idx & 63;
            float4v v = *(const float4v*)(rgb_w + idx);
            bf16x4 h;
            #pragma unroll
            for (int j = 0; j < 4; ++j) h[j] = (bf16)v[j];
            *(bf16x4*)(ldsWR + swz128(o, c * 2)) = h;
            v = *(const float4v*)(dep_w + idx);
            #pragma unroll
            for (int j = 0; j < 4; ++j) h[j] = (bf16)v[j];
            *(bf16x4*)(ldsWD + swz128(o, c * 2)) = h;
        }
        if (tid < 64) {
            float sc = bn1_g[tid] * rsqrtf(bn1_v[tid] + 1e-5f);
            s1[tid] = sc;
            b1[tid] = bn1_b[tid] - bn1_m[tid] * sc;
        }
    }
    __syncthreads();

    // ---- fragments -> registers ----
    bf16x8 aW[8], aR[2], aD[2];
    {
        const unsigned char* ldsW  = smem + OW_W;
        const unsigned char* ldsWR = smem + OW_WR;
        const unsigned char* ldsWD = smem + OW_WD;
        const int row = ot + l15;
        #pragma unroll
        for (int kk = 0; kk < 8; ++kk)
            aW[kk] = *(const bf16x8*)(ldsW + swz512(row, (kk * 32 + lg * 8) * 2));
        #pragma unroll
        for (int kk = 0; kk < 2; ++kk) {
            aR[kk] = *(const bf16x8*)(ldsWR + swz128(row, (kk * 32 + lg * 8) * 2));
            aD[kk] = *(const bf16x8*)(ldsWD + swz128(row, (kk * 32 + lg * 8) * 2));
        }
    }
    __syncthreads();

    // ---- phase T: stage dep/rgb tiles coalesced ----
    unsigned char* ldsC = smem + OT_C;
    unsigned char* ldsR = smem + OT_R;
    unsigned char* ldsD = smem + OT_D;
    const float* depb = dep + (size_t)b * 256 * 4096;
    const float* rgbb = rgb + (size_t)b * 64 * 4096;
    {
        const int c0 = tid >> 3, seg = tid & 7;
        #pragma unroll
        for (int r = 0; r < 4; ++r) {
            const int c = r * 64 + c0;
            float4v v = *(const float4v*)(depb + (size_t)c * 4096 + p0 + seg * 4);
            #pragma unroll
            for (int k = 0; k < 4; ++k)
                *(bf16*)(ldsC + swz512(seg * 4 + k, c * 2)) = (bf16)v[k];
        }
        float4v v = *(const float4v*)(rgbb + (size_t)c0 * 4096 + p0 + seg * 4);
        #pragma unroll
        for (int k = 0; k < 4; ++k)
            *(bf16*)(ldsR + swz128(seg * 4 + k, c0 * 2)) = (bf16)v[k];
    }
    __syncthreads();

    // ---- conv MFMA K=256 ----
    const int prow = ph * 16 + l15;
    f32x4 acc = {0.f, 0.f, 0.f, 0.f};
    #pragma unroll
    for (int kk = 0; kk < 8; ++kk) {
        bf16x8 bF = *(const bf16x8*)(ldsC + swz512(prow, (kk * 32 + lg * 8) * 2));
        acc = MFMA_BF16(aW[kk], bF, acc);
    }
    {
        const int o0 = ot + lg * 4;
        bf16x4 v4;
        #pragma unroll
        for (int r = 0; r < 4; ++r) {
            float x = acc[r] * s1[o0 + r] + b1[o0 + r];
            v4[r] = (bf16)(x > 0.f ? x : 0.f);
        }
        *(bf16x4*)(ldsD + swz128(prow, o0 * 2)) = v4;
    }
    __syncthreads();

    // ---- proj GEMMs (K=64) + fragment-order stores ----
    f32x4 accR = {0.f, 0.f, 0.f, 0.f}, accD = {0.f, 0.f, 0.f, 0.f};
    #pragma unroll
    for (int kk = 0; kk < 2; ++kk) {
        const int cb = (kk * 32 + lg * 8) * 2;
        bf16x8 bR = *(const bf16x8*)(ldsR + swz128(prow, cb));
        bf16x8 bD = *(const bf16x8*)(ldsD + swz128(prow, cb));
        accR = MFMA_BF16(aR[kk], bR, accR);
        accD = MFMA_BF16(aD[kk], bD, accD);
    }
    {
        const int o0 = ot + lg * 4;
        const size_t itile = (size_t)tile * 2 + ph;
        const size_t fbase = (size_t)b * 262144 + itile * 1024;
        const size_t prOff = fbase + (size_t)(o0 >> 3) * 128 + l15 * 8 + (o0 & 7);
        bf16x4 vR, vD;
        #pragma unroll
        for (int r = 0; r < 4; ++r) {
            vR[r] = (bf16)(accR[r] * K_E);
            vD[r] = (bf16)accD[r];
        }
        *(bf16x4*)(prF + prOff) = vR;
        *(bf16x4*)(pdF + prOff) = vD;
        const size_t pvBase = fbase + (ot4 >> 1) * 512 + (l15 >> 2) * 128
                            + lg * 32 + (ot4 & 1) * 4 + (l15 & 3);
        #pragma unroll
        for (int r = 0; r < 4; ++r)
            pvF[pvBase + r * 8] = (bf16)(accR[r] + accD[r]);
    }

    // ---- rgbd per-tile sums ----
    {
        const int c = tid & 63, g8 = tid >> 6;
        float sum = 0.f;
        #pragma unroll
        for (int q = 0; q < 4; ++q) {
            const int pp = g8 * 4 + q;
            sum += (float)*(const bf16*)(ldsR + swz128(pp, c * 2))
                 + (float)*(const bf16*)(ldsD + swz128(pp, c * 2));
        }
        red[g8 * 64 + c] = sum;
    }
    __syncthreads();
    if (tid < 64) {
        float s = 0.f;
        #pragma unroll
        for (int g = 0; g < 8; ++g) s += red[g * 64 + tid];
        rgbdPart[((size_t)b * 128 + tile) * 64 + tid] = s;
    }
}

// ---------------------------------------------------------------------------
// K_B: async-staged single-pass column stats. 256 blocks (4b x 64 j-chunks)
// x 512 thr. Wave w streams i-tiles {8t+w}; per super-tile stages its 4KB
// slice (pr 2KB + pv 2KB) via 4x global_load_lds(16B) into a wave-private
// dbuf; vmcnt(4) counted wait; no barriers in the loop. Last-block MLP gate.
// ---------------------------------------------------------------------------
#define STAGE(st, sl)                                                         \
    {                                                                         \
        const unsigned char* gp_ = prbB + (size_t)(st) * 16384 + w * 2048     \
                                 + lane * 16;                                 \
        unsigned char* lp_ = ring + (sl) * 32768 + w * 2048;                  \
        gload_lds16(gp_, lp_);                                                \
        gload_lds16(gp_ + 1024, lp_ + 1024);                                  \
        const unsigned char* gv_ = pvbB + (size_t)(st) * 16384 + w * 2048     \
                                 + lane * 16;                                 \
        unsigned char* lv_ = ring + (sl) * 32768 + 16384 + w * 2048;          \
        gload_lds16(gv_, lv_);                                                \
        gload_lds16(gv_ + 1024, lv_ + 1024);                                  \
    }

#define COMPUTESET(sl)                                                        \
    {                                                                         \
        const unsigned char* prS_ = ring + (sl) * 32768 + w * 2048;           \
        const unsigned char* pvS_ = ring + (sl) * 32768 + 16384 + w * 2048;   \
        bf16x8 A0 = *(const bf16x8*)(prS_ + lane * 16);                       \
        bf16x8 A1 = *(const bf16x8*)(prS_ + 1024 + lane * 16);                \
        bf16x8 V01 = *(const bf16x8*)(pvS_ + lane * 16);                      \
        bf16x8 V23 = *(const bf16x8*)(pvS_ + 1024 + lane * 16);               \
        const s4 v0_ = __builtin_bit_cast(s4, lo8(V01));                      \
        const s4 v1_ = __builtin_bit_cast(s4, hi8(V01));                      \
        const s4 v2_ = __builtin_bit_cast(s4, lo8(V23));                      \
        const s4 v3_ = __builtin_bit_cast(s4, hi8(V23));                      \
        _Pragma("unroll")                                                     \
        for (int jt = 0; jt < 4; ++jt) {                                      \
            f32x4 e = {0.f, 0.f, 0.f, 0.f};                                   \
            e = MFMA_BF16(A0, B0[jt], e);                                     \
            e = MFMA_BF16(A1, B1[jt], e);                                     \
            bf16x4 ph_;                                                       \
            _Pragma("unroll")                                                 \
            for (int r = 0; r < 4; ++r) {                                     \
                float pf_ = EXP2(e[r]);                                       \
                z[jt] += pf_;                                                 \
                ph_[r] = (bf16)pf_;                                           \
            }                                                                 \
            const s4 pB_ = __builtin_bit_cast(s4, ph_);                       \
            acc[jt][0] = MFMA16(v0_, pB_, acc[jt][0]);                        \
            acc[jt][1] = MFMA16(v1_, pB_, acc[jt][1]);                        \
            acc[jt][2] = MFMA16(v2_, pB_, acc[jt][2]);                        \
            acc[jt][3] = MFMA16(v3_, pB_, acc[jt][3]);                        \
        }                                                                     \
    }

#define WAIT_VM4   asm volatile("s_waitcnt vmcnt(4)" ::: "memory")
#define WAIT_VM0   asm volatile("s_waitcnt vmcnt(0)" ::: "memory")
#define WAIT_LGKM0 asm volatile("s_waitcnt lgkmcnt(0)" ::: "memory")

__global__ __launch_bounds__(512, 2) void k_col(
    const bf16* __restrict__ prF, const bf16* __restrict__ pdF,
    const bf16* __restrict__ pvF,
    float* __restrict__ gapPart, const float* __restrict__ rgbdPart,
    int* __restrict__ counter,
    const float* __restrict__ mlp1_w,
    const float* __restrict__ bn2_g, const float* __restrict__ bn2_b,
    const float* __restrict__ bn2_m, const float* __restrict__ bn2_v,
    const float* __restrict__ mlp2_w,
    const float* __restrict__ bn3_g, const float* __restrict__ bn3_b,
    const float* __restrict__ bn3_m, const float* __restrict__ bn3_v,
    float* __restrict__ out)
{
    const int bid = blockIdx.x;
    const int xcd = bid & 7, b = xcd >> 1;
    const int jt64 = ((bid >> 3) << 1) | (xcd & 1);   // 0..63
    const int tid = threadIdx.x;
    const int w = tid >> 6, lane = tid & 63;
    const int l15 = lane & 15, lg = lane >> 4;

    __shared__ __align__(16) unsigned char ring[65536];   // 2 slots x 8 waves x 4KB
    __shared__ float zred[8][64];
    __shared__ float zfull[64];
    __shared__ float gred[8][64];
    __shared__ float gv4[4][64];
    __shared__ float h4[4][24];
    __shared__ int winflag;
    if (tid == 0) winflag = 0;

    const bf16* prb = prF + (size_t)b * 262144;
    const bf16* pdb = pdF + (size_t)b * 262144;
    const bf16* pvb = pvF + (size_t)b * 262144;
    const unsigned char* prbB = (const unsigned char*)prb;
    const unsigned char* pvbB = (const unsigned char*)pvb;

    // resident b-frags for 4 j-subtiles
    bf16x8 B0[4], B1[4];
    #pragma unroll
    for (int jt = 0; jt < 4; ++jt) {
        const bf16* q = pdb + (size_t)(jt64 * 4 + jt) * 1024 + lane * 8;
        B0[jt] = *(const bf16x8*)q;
        B1[jt] = *(const bf16x8*)(q + 512);
    }

    f32x4 acc[4][4];
    #pragma unroll
    for (int jt = 0; jt < 4; ++jt)
        #pragma unroll
        for (int cb = 0; cb < 4; ++cb)
            acc[jt][cb] = (f32x4){0.f, 0.f, 0.f, 0.f};
    float z[4] = {0.f, 0.f, 0.f, 0.f};

    // ---- async pipeline: 32 super-tiles of 128 i (wave w owns i-tile 8t+w) --
    STAGE(0, 0);
    STAGE(1, 1);
    for (int t = 0; t < 30; ++t) {
        WAIT_VM4;                    // tile t's 4 DMA ops done (t+1 in flight)
        COMPUTESET(t & 1);
        WAIT_LGKM0;                  // ds_reads drained before slot overwrite
        STAGE(t + 2, t & 1);
    }
    WAIT_VM4;  COMPUTESET(0);        // t=30
    WAIT_VM0;  COMPUTESET(1);        // t=31

    // ---- Z reduce ----
    #pragma unroll
    for (int jt = 0; jt < 4; ++jt) {
        float zv = z[jt];
        zv += __shfl_xor(zv, 16);
        zv += __shfl_xor(zv, 32);
        if (lane < 16) zred[w][jt * 16 + lane] = zv;
    }
    __syncthreads();
    if (tid < 64) {
        float s = 0.f;
        #pragma unroll
        for (int k = 0; k < 8; ++k) s += zred[k][tid];
        zfull[tid] = s;
    }
    __syncthreads();

    // ---- g[c] = sum_jt sum_l15 acc*zinv ----
    float zinv[4];
    #pragma unroll
    for (int jt = 0; jt < 4; ++jt) {
        const float zj = zfull[jt * 16 + l15];
        float zi = __builtin_amdgcn_rcpf(zj);
        zinv[jt] = zi * (2.0f - zj * zi);
    }
    #pragma unroll
    for (int cb = 0; cb < 4; ++cb) {
        #pragma unroll
        for (int r = 0; r < 4; ++r) {
            float v = acc[0][cb][r] * zinv[0] + acc[1][cb][r] * zinv[1]
                    + acc[2][cb][r] * zinv[2] + acc[3][cb][r] * zinv[3];
            v += __shfl_xor(v, 1);
            v += __shfl_xor(v, 2);
            v += __shfl_xor(v, 4);
            v += __shfl_xor(v, 8);
            if (l15 == 0) gred[w][cb * 16 + lg * 4 + r] = v;
        }
    }
    __syncthreads();
    if (tid < 64) {
        float s = 0.f;
        #pragma unroll
        for (int k = 0; k < 8; ++k) s += gred[k][tid];
        gapPart[((size_t)b * 64 + jt64) * 64 + tid] = s;
        __threadfence();
        int old = atomicAdd(counter, 1);
        if (old == 256 * 64 - 1) winflag = 1;
    }
    __syncthreads();

    // ================= last block: MLP gate ==================
    if (winflag) {
        __threadfence();
        const int wb = w >> 1, half = w & 1;
        float acc2 = 0.f;
        const float* gp = gapPart + ((size_t)wb * 64 + half * 32) * 64 + lane;
        #pragma unroll 4
        for (int r = 0; r < 32; ++r) acc2 += gp[r * 64];
        const float* rp = rgbdPart + ((size_t)wb * 128 + half * 64) * 64 + lane;
        #pragma unroll 4
        for (int r = 0; r < 64; ++r) acc2 += rp[r * 64];
        gred[w][lane] = acc2;
        __syncthreads();
        if (tid < 256) {
            const int b4 = tid >> 6, c = tid & 63;
            gv4[b4][c] = (gred[2 * b4][c] + gred[2 * b4 + 1][c]) * (1.f / 4096.f);
        }
        __syncthreads();
        if (tid < 96) {
            const int b4 = tid / 24, o = tid % 24;
            float a = 0.f;
            #pragma unroll
            for (int cc = 0; cc < 64; ++cc) a += mlp1_w[o * 64 + cc] * gv4[b4][cc];
            float sc = bn2_g[o] * rsqrtf(bn2_v[o] + 1e-5f);
            a = a * sc + bn2_b[o] - bn2_m[o] * sc;
            h4[b4][o] = a > 0.f ? a : 0.f;
        }
        __syncthreads();
        if (tid < 256) {
            const int b4 = tid >> 6, c = tid & 63;
            float u = 0.f;
            #pragma unroll
            for (int o = 0; o < 24; ++o) u += mlp2_w[c * 24 + o] * h4[b4][o];
            float sc = bn3_g[c] * rsqrtf(bn3_v[c] + 1e-5f);
            u = u * sc + bn3_b[c] - bn3_m[c] * sc;
            out[b4 * 64 + c] = 1.f / (1.f + __expf(-u));
        }
    }
}

// ---------------------------------------------------------------------------
extern "C" void kernel_launch(void* const* d_in, const int* in_sizes, int n_in,
                              void* d_out, int out_size, void* d_ws, size_t ws_size,
                              hipStream_t stream)
{
    const float* rgb    = (const float*)d_in[0];
    const float* dep    = (const float*)d_in[1];
    const float* conv_w = (const float*)d_in[2];
    const float* bn1_g  = (const float*)d_in[3];
    const float* bn1_b  = (const float*)d_in[4];
    const float* bn1_m  = (const float*)d_in[5];
    const float* bn1_v  = (const float*)d_in[6];
    const float* rgb_w  = (const float*)d_in[7];
    const float* dep_w  = (const float*)d_in[8];
    const float* mlp1_w = (const float*)d_in[9];
    const float* bn2_g  = (const float*)d_in[10];
    const float* bn2_b  = (const float*)d_in[11];
    const float* bn2_m  = (const float*)d_in[12];
    const float* bn2_v  = (const float*)d_in[13];
    const float* mlp2_w = (const float*)d_in[14];
    const float* bn3_g  = (const float*)d_in[15];
    const float* bn3_b  = (const float*)d_in[16];
    const float* bn3_m  = (const float*)d_in[17];
    const float* bn3_v  = (const float*)d_in[18];

    char* ws = (char*)d_ws;
    bf16*  prF      = (bf16*)(ws);                                  // 2 MB
    bf16*  pdF      = (bf16*)(ws + (2u << 20));                     // 2 MB
    bf16*  pvF      = (bf16*)(ws + (4u << 20));                     // 2 MB
    float* rgbdPart = (float*)(ws + (6u << 20));                    // 128 KB
    float* gapPart  = (float*)(ws + (6u << 20) + (128u << 10));     // 64 KB
    int*   counter  = (int*)  (ws + (6u << 20) + (192u << 10));     // 4 B

    k_front<<<512, 512, 0, stream>>>(rgb, dep, conv_w,
                                     bn1_g, bn1_b, bn1_m, bn1_v,
                                     rgb_w, dep_w,
                                     prF, pdF, pvF, rgbdPart, counter);
    k_col<<<256, 512, 0, stream>>>(prF, pdF, pvF, gapPart, rgbdPart, counter,
                                   mlp1_w, bn2_g, bn2_b, bn2_m, bn2_v,
                                   mlp2_w, bn3_g, bn3_b, bn3_m, bn3_v,
                                   (float*)d_out);
}